// Round 1
// baseline (84.691 us; speedup 1.0000x reference)
//
#include <hip/hip_runtime.h>
#include <hip/hip_bf16.h>

// Problem constants (from reference)
#define BATCH    2048
#define N_LABELS 10000
#define HIDDEN   768
#define N_EDGES  20000
#define PENALTY  1e-4f

constexpr int BCE_THREADS = 256;
constexpr int BCE_BLOCKS  = 2048;                 // grid-stride over 5.12M float4
constexpr int REG_THREADS = 256;
constexpr int EDGES_PER_BLOCK = REG_THREADS / 64; // 4 waves -> 4 edges per block
constexpr int REG_BLOCKS  = N_EDGES / EDGES_PER_BLOCK; // 5000

// stable softplus(x) - t*x
__device__ __forceinline__ float bce_term(float x, float t) {
    float sp = fmaxf(x, 0.0f) + log1pf(__expf(-fabsf(x)));
    return sp - t * x;
}

__device__ __forceinline__ float wave_reduce(float v) {
#pragma unroll
    for (int o = 32; o > 0; o >>= 1) v += __shfl_down(v, o, 64);
    return v;
}

// ---------------- BCE: mean(softplus(x) - t*x) ----------------
template <bool USE_ATOMIC>
__global__ void __launch_bounds__(BCE_THREADS)
bce_kernel(const float4* __restrict__ x4, const float4* __restrict__ t4,
           float* __restrict__ dst) {
    const int n4 = (BATCH * N_LABELS) / 4;  // 5,120,000
    float acc = 0.0f;
    for (int i = blockIdx.x * blockDim.x + threadIdx.x; i < n4;
         i += gridDim.x * blockDim.x) {
        float4 x = x4[i];
        float4 t = t4[i];
        acc += bce_term(x.x, t.x) + bce_term(x.y, t.y) +
               bce_term(x.z, t.z) + bce_term(x.w, t.w);
    }
    acc = wave_reduce(acc);
    __shared__ float s[BCE_THREADS / 64];
    const int lane = threadIdx.x & 63, w = threadIdx.x >> 6;
    if (lane == 0) s[w] = acc;
    __syncthreads();
    if (threadIdx.x == 0) {
        float b = 0.0f;
#pragma unroll
        for (int i = 0; i < BCE_THREADS / 64; ++i) b += s[i];
        b *= (1.0f / ((float)BATCH * (float)N_LABELS));  // pre-scale: mean
        if (USE_ATOMIC) atomicAdd(dst, b);
        else            dst[blockIdx.x] = b;
    }
}

// -------- reg: 0.5 * sum ||params[p] - params[c]||^2, one wave/edge --------
template <bool USE_ATOMIC>
__global__ void __launch_bounds__(REG_THREADS)
reg_kernel(const float* __restrict__ params, const int* __restrict__ pidx,
           const int* __restrict__ cidx, float* __restrict__ dst) {
    const int wave = threadIdx.x >> 6;
    const int lane = threadIdx.x & 63;
    const int edge = blockIdx.x * EDGES_PER_BLOCK + wave;

    const int p = pidx[edge];
    const int c = cidx[edge];
    const float4* rp = (const float4*)(params + (size_t)p * HIDDEN);
    const float4* rc = (const float4*)(params + (size_t)c * HIDDEN);

    float acc = 0.0f;
#pragma unroll
    for (int j = 0; j < HIDDEN / 4 / 64; ++j) {  // 3 iters, coalesced float4
        float4 a = rp[j * 64 + lane];
        float4 b = rc[j * 64 + lane];
        float dx = a.x - b.x, dy = a.y - b.y, dz = a.z - b.z, dw = a.w - b.w;
        acc = fmaf(dx, dx, acc);
        acc = fmaf(dy, dy, acc);
        acc = fmaf(dz, dz, acc);
        acc = fmaf(dw, dw, acc);
    }
    acc = wave_reduce(acc);
    __shared__ float s[EDGES_PER_BLOCK];
    if (lane == 0) s[wave] = acc;
    __syncthreads();
    if (threadIdx.x == 0) {
        float b = 0.0f;
#pragma unroll
        for (int i = 0; i < EDGES_PER_BLOCK; ++i) b += s[i];
        b *= (0.5f * PENALTY);  // pre-scale
        if (USE_ATOMIC) atomicAdd(dst, b);
        else            dst[blockIdx.x] = b;
    }
}

// ---------------- finalize: deterministic sum of partials ----------------
__global__ void __launch_bounds__(256)
finalize_kernel(const float* __restrict__ partials, int n, float* __restrict__ out) {
    float acc = 0.0f;
    for (int i = threadIdx.x; i < n; i += blockDim.x) acc += partials[i];
    acc = wave_reduce(acc);
    __shared__ float s[4];
    const int lane = threadIdx.x & 63, w = threadIdx.x >> 6;
    if (lane == 0) s[w] = acc;
    __syncthreads();
    if (threadIdx.x == 0) out[0] = s[0] + s[1] + s[2] + s[3];
}

extern "C" void kernel_launch(void* const* d_in, const int* in_sizes, int n_in,
                              void* d_out, int out_size, void* d_ws, size_t ws_size,
                              hipStream_t stream) {
    const float* logits  = (const float*)d_in[0];
    const float* targets = (const float*)d_in[1];
    const float* params  = (const float*)d_in[2];
    const int*   pidx    = (const int*)d_in[3];
    const int*   cidx    = (const int*)d_in[4];
    float* out = (float*)d_out;

    const size_t need = (size_t)(BCE_BLOCKS + REG_BLOCKS) * sizeof(float);
    if (ws_size >= need) {
        // deterministic path: per-block partials in ws, single-block finalize
        float* partials = (float*)d_ws;
        bce_kernel<false><<<BCE_BLOCKS, BCE_THREADS, 0, stream>>>(
            (const float4*)logits, (const float4*)targets, partials);
        reg_kernel<false><<<REG_BLOCKS, REG_THREADS, 0, stream>>>(
            params, pidx, cidx, partials + BCE_BLOCKS);
        finalize_kernel<<<1, 256, 0, stream>>>(partials, BCE_BLOCKS + REG_BLOCKS, out);
    } else {
        // fallback: atomic accumulation directly into d_out
        hipMemsetAsync(d_out, 0, sizeof(float), stream);
        bce_kernel<true><<<BCE_BLOCKS, BCE_THREADS, 0, stream>>>(
            (const float4*)logits, (const float4*)targets, out);
        reg_kernel<true><<<REG_BLOCKS, REG_THREADS, 0, stream>>>(
            params, pidx, cidx, out);
    }
}

// Round 2
// 49.308 us; speedup vs baseline: 1.7176x; 1.7176x over previous
//
#include <hip/hip_runtime.h>
#include <hip/hip_bf16.h>

// Problem constants (from reference)
#define BATCH    2048
#define N_LABELS 10000
#define HIDDEN   768
#define N_EDGES  20000
#define PENALTY  1e-4f

constexpr int BCE_THREADS = 256;
constexpr int BCE_BLOCKS  = 2048;                 // grid-stride over 5.12M float4
constexpr int REG_THREADS = 256;
constexpr int EDGES_PER_BLOCK = REG_THREADS / 64; // 4 waves -> 4 edges per block
constexpr int REG_BLOCKS  = N_EDGES / EDGES_PER_BLOCK; // 5000
constexpr int FIN_THREADS = 1024;

// stable softplus(x) - t*x using raw HW transcendentals:
// softplus(x) = max(x,0) + ln2 * log2(1 + 2^(-|x|*log2e))
// v_exp_f32 = 2^x, v_log_f32 = log2(x): ~8 ops/elem vs ~60 for libm log1pf.
__device__ __forceinline__ float bce_term(float x, float t) {
    float e = __builtin_amdgcn_exp2f(fabsf(x) * -1.44269504f); // e^{-|x|}
    float l = __builtin_amdgcn_logf(1.0f + e);                 // log2(1+e)
    return fmaxf(x, 0.0f) + 0.69314718f * l - t * x;
}

__device__ __forceinline__ float wave_reduce(float v) {
#pragma unroll
    for (int o = 32; o > 0; o >>= 1) v += __shfl_down(v, o, 64);
    return v;
}

// ---------------- BCE: mean(softplus(x) - t*x) ----------------
template <bool USE_ATOMIC>
__global__ void __launch_bounds__(BCE_THREADS)
bce_kernel(const float4* __restrict__ x4, const float4* __restrict__ t4,
           float* __restrict__ dst) {
    const int n4 = (BATCH * N_LABELS) / 4;  // 5,120,000
    float acc = 0.0f;
    for (int i = blockIdx.x * blockDim.x + threadIdx.x; i < n4;
         i += gridDim.x * blockDim.x) {
        float4 x = x4[i];
        float4 t = t4[i];
        acc += bce_term(x.x, t.x) + bce_term(x.y, t.y) +
               bce_term(x.z, t.z) + bce_term(x.w, t.w);
    }
    acc = wave_reduce(acc);
    __shared__ float s[BCE_THREADS / 64];
    const int lane = threadIdx.x & 63, w = threadIdx.x >> 6;
    if (lane == 0) s[w] = acc;
    __syncthreads();
    if (threadIdx.x == 0) {
        float b = 0.0f;
#pragma unroll
        for (int i = 0; i < BCE_THREADS / 64; ++i) b += s[i];
        b *= (1.0f / ((float)BATCH * (float)N_LABELS));  // pre-scale: mean
        if (USE_ATOMIC) atomicAdd(dst, b);
        else            dst[blockIdx.x] = b;
    }
}

// -------- reg: 0.5 * sum ||params[p] - params[c]||^2, one wave/edge --------
template <bool USE_ATOMIC>
__global__ void __launch_bounds__(REG_THREADS)
reg_kernel(const float* __restrict__ params, const int* __restrict__ pidx,
           const int* __restrict__ cidx, float* __restrict__ dst) {
    const int wave = threadIdx.x >> 6;
    const int lane = threadIdx.x & 63;
    const int edge = blockIdx.x * EDGES_PER_BLOCK + wave;

    const int p = pidx[edge];
    const int c = cidx[edge];
    const float4* rp = (const float4*)(params + (size_t)p * HIDDEN);
    const float4* rc = (const float4*)(params + (size_t)c * HIDDEN);

    float acc = 0.0f;
#pragma unroll
    for (int j = 0; j < HIDDEN / 4 / 64; ++j) {  // 3 iters, coalesced float4
        float4 a = rp[j * 64 + lane];
        float4 b = rc[j * 64 + lane];
        float dx = a.x - b.x, dy = a.y - b.y, dz = a.z - b.z, dw = a.w - b.w;
        acc = fmaf(dx, dx, acc);
        acc = fmaf(dy, dy, acc);
        acc = fmaf(dz, dz, acc);
        acc = fmaf(dw, dw, acc);
    }
    acc = wave_reduce(acc);
    __shared__ float s[EDGES_PER_BLOCK];
    if (lane == 0) s[wave] = acc;
    __syncthreads();
    if (threadIdx.x == 0) {
        float b = 0.0f;
#pragma unroll
        for (int i = 0; i < EDGES_PER_BLOCK; ++i) b += s[i];
        b *= (0.5f * PENALTY);  // pre-scale
        if (USE_ATOMIC) atomicAdd(dst, b);
        else            dst[blockIdx.x] = b;
    }
}

// ---------------- finalize: deterministic sum of partials ----------------
__global__ void __launch_bounds__(FIN_THREADS)
finalize_kernel(const float* __restrict__ partials, int n, float* __restrict__ out) {
    float acc = 0.0f;
    for (int i = threadIdx.x; i < n; i += blockDim.x) acc += partials[i];
    acc = wave_reduce(acc);
    __shared__ float s[FIN_THREADS / 64];
    const int lane = threadIdx.x & 63, w = threadIdx.x >> 6;
    if (lane == 0) s[w] = acc;
    __syncthreads();
    if (threadIdx.x == 0) {
        float b = 0.0f;
#pragma unroll
        for (int i = 0; i < FIN_THREADS / 64; ++i) b += s[i];
        out[0] = b;
    }
}

extern "C" void kernel_launch(void* const* d_in, const int* in_sizes, int n_in,
                              void* d_out, int out_size, void* d_ws, size_t ws_size,
                              hipStream_t stream) {
    const float* logits  = (const float*)d_in[0];
    const float* targets = (const float*)d_in[1];
    const float* params  = (const float*)d_in[2];
    const int*   pidx    = (const int*)d_in[3];
    const int*   cidx    = (const int*)d_in[4];
    float* out = (float*)d_out;

    const size_t need = (size_t)(BCE_BLOCKS + REG_BLOCKS) * sizeof(float);
    if (ws_size >= need) {
        // deterministic path: per-block partials in ws, single-block finalize
        float* partials = (float*)d_ws;
        bce_kernel<false><<<BCE_BLOCKS, BCE_THREADS, 0, stream>>>(
            (const float4*)logits, (const float4*)targets, partials);
        reg_kernel<false><<<REG_BLOCKS, REG_THREADS, 0, stream>>>(
            params, pidx, cidx, partials + BCE_BLOCKS);
        finalize_kernel<<<1, FIN_THREADS, 0, stream>>>(partials, BCE_BLOCKS + REG_BLOCKS, out);
    } else {
        // fallback: atomic accumulation directly into d_out
        hipMemsetAsync(d_out, 0, sizeof(float), stream);
        bce_kernel<true><<<BCE_BLOCKS, BCE_THREADS, 0, stream>>>(
            (const float4*)logits, (const float4*)targets, out);
        reg_kernel<true><<<REG_BLOCKS, REG_THREADS, 0, stream>>>(
            params, pidx, cidx, out);
    }
}

// Round 3
// 48.178 us; speedup vs baseline: 1.7579x; 1.0235x over previous
//
#include <hip/hip_runtime.h>
#include <hip/hip_bf16.h>

// Problem constants (from reference)
#define BATCH    2048
#define N_LABELS 10000
#define HIDDEN   768
#define N_EDGES  20000
#define PENALTY  1e-4f

constexpr int THREADS   = 256;
constexpr int N4        = BATCH * N_LABELS / 4;   // 5,120,000 float4 pairs
constexpr int BCE_K     = 10;                     // float4s per thread (deep MLP)
constexpr int BCE_STRIDE = N4 / BCE_K;            // 512,000 threads
constexpr int BCE_BLOCKS = BCE_STRIDE / THREADS;  // 2000 (exact, no tail)
constexpr int EDGES_PER_BLOCK = THREADS / 64;     // 4 waves -> 4 edges/block
constexpr int REG_BLOCKS = N_EDGES / EDGES_PER_BLOCK;     // 5000
constexpr int TOTAL_BLOCKS = BCE_BLOCKS + REG_BLOCKS;     // 7000
constexpr int FIN_THREADS = 1024;

// stable softplus(x) - t*x via raw HW transcendentals:
// softplus(x) = max(x,0) + ln2 * log2(1 + 2^(-|x|*log2e))
__device__ __forceinline__ float bce_term(float x, float t) {
    float e = __builtin_amdgcn_exp2f(fabsf(x) * -1.44269504f); // e^{-|x|}
    float l = __builtin_amdgcn_logf(1.0f + e);                 // log2(1+e)
    return fmaxf(x, 0.0f) + 0.69314718f * l - t * x;
}

__device__ __forceinline__ float wave_reduce(float v) {
#pragma unroll
    for (int o = 32; o > 0; o >>= 1) v += __shfl_down(v, o, 64);
    return v;
}

// ---- fused: blocks [0,BCE_BLOCKS) do BCE, rest do edge regularizer ----
template <bool USE_ATOMIC>
__global__ void __launch_bounds__(THREADS)
fused_kernel(const float4* __restrict__ x4, const float4* __restrict__ t4,
             const float* __restrict__ params, const int* __restrict__ pidx,
             const int* __restrict__ cidx, float* __restrict__ dst) {
    const int lane = threadIdx.x & 63;
    const int w    = threadIdx.x >> 6;
    __shared__ float s[THREADS / 64];

    if (blockIdx.x < BCE_BLOCKS) {
        // ---------- BCE: mean(softplus(x) - t*x) ----------
        const int tid = blockIdx.x * THREADS + threadIdx.x;
        // Issue all 20 independent 16B loads before any compute: deep MLP.
        float4 xs[BCE_K], ts[BCE_K];
#pragma unroll
        for (int j = 0; j < BCE_K; ++j) xs[j] = x4[tid + j * BCE_STRIDE];
#pragma unroll
        for (int j = 0; j < BCE_K; ++j) ts[j] = t4[tid + j * BCE_STRIDE];

        float acc = 0.0f;
#pragma unroll
        for (int j = 0; j < BCE_K; ++j) {
            acc += bce_term(xs[j].x, ts[j].x) + bce_term(xs[j].y, ts[j].y) +
                   bce_term(xs[j].z, ts[j].z) + bce_term(xs[j].w, ts[j].w);
        }
        acc = wave_reduce(acc);
        if (lane == 0) s[w] = acc;
        __syncthreads();
        if (threadIdx.x == 0) {
            float b = (s[0] + s[1] + s[2] + s[3]) *
                      (1.0f / ((float)BATCH * (float)N_LABELS));
            if (USE_ATOMIC) atomicAdd(dst, b);
            else            dst[blockIdx.x] = b;
        }
    } else {
        // ---- reg: 0.5*PENALTY * sum ||params[p]-params[c]||^2, 1 wave/edge ----
        const int edge = (blockIdx.x - BCE_BLOCKS) * EDGES_PER_BLOCK + w;
        const int p = pidx[edge];
        const int c = cidx[edge];
        const float4* rp = (const float4*)(params + (size_t)p * HIDDEN);
        const float4* rc = (const float4*)(params + (size_t)c * HIDDEN);

        // 6 independent float4 loads up front, then FMAs.
        float4 a[3], b[3];
#pragma unroll
        for (int j = 0; j < 3; ++j) a[j] = rp[j * 64 + lane];
#pragma unroll
        for (int j = 0; j < 3; ++j) b[j] = rc[j * 64 + lane];

        float acc = 0.0f;
#pragma unroll
        for (int j = 0; j < 3; ++j) {
            float dx = a[j].x - b[j].x, dy = a[j].y - b[j].y;
            float dz = a[j].z - b[j].z, dw = a[j].w - b[j].w;
            acc = fmaf(dx, dx, acc);
            acc = fmaf(dy, dy, acc);
            acc = fmaf(dz, dz, acc);
            acc = fmaf(dw, dw, acc);
        }
        acc = wave_reduce(acc);
        if (lane == 0) s[w] = acc;
        __syncthreads();
        if (threadIdx.x == 0) {
            float b2 = (s[0] + s[1] + s[2] + s[3]) * (0.5f * PENALTY);
            if (USE_ATOMIC) atomicAdd(dst, b2);
            else            dst[blockIdx.x] = b2;
        }
    }
}

// ---------------- finalize: deterministic sum of partials ----------------
__global__ void __launch_bounds__(FIN_THREADS)
finalize_kernel(const float* __restrict__ partials, int n, float* __restrict__ out) {
    float acc = 0.0f;
    for (int i = threadIdx.x; i < n; i += blockDim.x) acc += partials[i];
    acc = wave_reduce(acc);
    __shared__ float s[FIN_THREADS / 64];
    const int lane = threadIdx.x & 63, w = threadIdx.x >> 6;
    if (lane == 0) s[w] = acc;
    __syncthreads();
    if (threadIdx.x == 0) {
        float b = 0.0f;
#pragma unroll
        for (int i = 0; i < FIN_THREADS / 64; ++i) b += s[i];
        out[0] = b;
    }
}

extern "C" void kernel_launch(void* const* d_in, const int* in_sizes, int n_in,
                              void* d_out, int out_size, void* d_ws, size_t ws_size,
                              hipStream_t stream) {
    const float* logits  = (const float*)d_in[0];
    const float* targets = (const float*)d_in[1];
    const float* params  = (const float*)d_in[2];
    const int*   pidx    = (const int*)d_in[3];
    const int*   cidx    = (const int*)d_in[4];
    float* out = (float*)d_out;

    const size_t need = (size_t)TOTAL_BLOCKS * sizeof(float);
    if (ws_size >= need) {
        // deterministic path: per-block partials in ws, single-block finalize
        float* partials = (float*)d_ws;
        fused_kernel<false><<<TOTAL_BLOCKS, THREADS, 0, stream>>>(
            (const float4*)logits, (const float4*)targets, params, pidx, cidx,
            partials);
        finalize_kernel<<<1, FIN_THREADS, 0, stream>>>(partials, TOTAL_BLOCKS, out);
    } else {
        // fallback: atomic accumulation directly into d_out
        hipMemsetAsync(d_out, 0, sizeof(float), stream);
        fused_kernel<true><<<TOTAL_BLOCKS, THREADS, 0, stream>>>(
            (const float4*)logits, (const float4*)targets, params, pidx, cidx,
            out);
    }
}